// Round 13
// baseline (133.089 us; speedup 1.0000x reference)
//
#include <hip/hip_runtime.h>
#include <math.h>

#define NS 100000
#define NC 64
#define ND 32
#define NK 576            // 18 k-tiles of 32 features
#define NBLK ((NS + 255) / 256)     // 391 main blocks, 256 samples each
#define QBYTES (NC * NK * 2)        // 73728 B
#define NCPB 8                      // components per setup block
#define LOG2PI 1.8378770664093453f

typedef __attribute__((ext_vector_type(8))) __bf16 bf16x8;
typedef __attribute__((ext_vector_type(8))) float  floatx8;
typedef __attribute__((ext_vector_type(4))) float  floatx4;

// ws layout (bytes):
//   Qf  [73728 B] : Q in MFMA a-fragment order: chunk (mt*18+t)*64 + quad*16
//         + colk holds 8 bf16 (16 B) for comp mt*16+colk, feats t*32+quad*8+jj.
//   lw  [NC floats] @ 73728 : log_softmax(log_weights)
//   kc  [NC floats] @ 73984 : kconst_k - 0.5*mu^T P mu (fp32)
//   pb  [NBLK floats] @ 74240 : per-block partials (no atomics anywhere)
//
// MEASURED LESSONS:
//  - R12: R11's "43us setup" rows were cold warm-up dispatches; steady-state
//    setup ~5us. Vectorized setup kept anyway (cheap, correct).
//  - R9: RUNTIME-bound 2-trip loop unrolled+interleaved -> scratch spill.
//    Compile-time 2-pair structure (R3/R4) did NOT spill. Main uses the
//    latter; LDS (72KB -> 2 blk/CU) caps occupancy, so VGPR headroom is 256.
//  - R5/R10: device fences + same-line ticket atomics cost 8-11us at ~800
//    blocks. Separate 1-block reduce kernel is cheaper.
//  - R8: LDS-staged Q in main beats per-wave L2 re-read.

// ---------------- setup helpers (all-literal indices -> registers) ----------

template<int I, int Q>
__device__ __forceinline__ void load_row(const floatx4* ls4, floatx4 (&rb)[8]) {
    if constexpr (Q <= I / 4) {
        rb[Q] = ls4[I * 8 + Q];          // ds_read_b128, wave-uniform broadcast
        load_row<I, Q + 1>(ls4, rb);
    }
}

template<int I, int L>
__device__ __forceinline__ void fchain(const floatx4 (&rb)[8], const float (&a)[ND], float& s) {
    if constexpr (L < I) {
        s = fmaf(-rb[L / 4][L % 4], a[L], s);
        fchain<I, L + 1>(rb, a, s);
    }
}

template<int I>
__device__ __forceinline__ void fsub2(const floatx4* ls4, float (&a)[ND], int j) {
    if constexpr (I < ND) {
        floatx4 rb[8];
        load_row<I, 0>(ls4, rb);
        float s = (I == j) ? 1.0f : 0.0f;
        fchain<I, 0>(rb, a, s);
        float v = s / rb[I / 4][I % 4];
        a[I] = (I < j) ? 0.0f : v;
        fsub2<I + 1>(ls4, a, j);
    }
}

template<int Q>
__device__ __forceinline__ void store_ac(float* acrow, const float (&a)[ND]) {
    if constexpr (Q < 8) {
        floatx4 t;
        t[0] = a[4 * Q + 0]; t[1] = a[4 * Q + 1];
        t[2] = a[4 * Q + 2]; t[3] = a[4 * Q + 3];
        *(floatx4*)(acrow + 4 * Q) = t;
        store_ac<Q + 1>(acrow, a);
    }
}

template<int JJ>
__device__ __forceinline__ void qpack(bf16x8& v, const float* Pc, const float* bbc,
                                      int t, int quad) {
    if constexpr (JJ < 8) {
        int u = quad * 8 + JJ;
        float val;
        if (t == 0)       val = -0.5f * Pc[u * 32 + u];
        else if (t < 16)  val = -Pc[u * 32 + ((u + t) & 31)];
        else if (t == 16) val = (u < 16) ? -Pc[u * 32 + u + 16] : bbc[u - 16];
        else              val = (u < 16) ? bbc[16 + u] : 0.0f;
        v[JJ] = (__bf16)val;
        qpack<JJ + 1>(v, Pc, bbc, t, quad);
    }
}

// 8 blocks x 512 threads; block b handles comps 8b..8b+7, one per wave.
__launch_bounds__(512)
__global__ void gmm_setup(const float* __restrict__ means,
                          const float* __restrict__ scale_tril,
                          const float* __restrict__ log_weights,
                          __bf16* __restrict__ Qf,
                          float* __restrict__ lw,
                          float* __restrict__ kc) {
    __shared__ __align__(16) floatx4 LsP4[NCPB * 256];   // 32 KB: L, later P
    __shared__ __align__(16) float Ac[NCPB][32][36];     // A=L^-1 cols as rows
    __shared__ float mu_s[NCPB][32];
    __shared__ float bb_s[NCPB][32];

    const int tid  = threadIdx.x;
    const int b    = blockIdx.x;
    const int w    = tid >> 6;          // comp-in-block
    const int lane = tid & 63;

    {
        const floatx4* g4 = (const floatx4*)scale_tril + (size_t)b * 2048;
#pragma unroll
        for (int q = 0; q < 4; ++q)
            LsP4[q * 512 + tid] = g4[q * 512 + tid];
        if (tid < NCPB * 32)
            mu_s[tid >> 5][tid & 31] = means[(size_t)(b * NCPB + (tid >> 5)) * ND + (tid & 31)];
    }
    __syncthreads();

    const floatx4* ls4 = LsP4 + w * 256;
    if (lane < ND) {
        float a[ND];
        fsub2<0>(ls4, a, lane);
        store_ac<0>(&Ac[w][lane][0], a);
    }
    float hv = (lane < ND) ? logf(((const float*)LsP4)[w * 1024 + lane * 33]) : 0.0f;
#pragma unroll
    for (int off = 1; off < 64; off <<= 1) hv += __shfl_xor(hv, off);
    float hld = hv;
    __syncthreads();

    {
        int c = tid >> 6, half = (tid >> 5) & 1, i = tid & 31;
        const floatx4* rI4 = (const floatx4*)&Ac[c][i][0];
        float* Pc = (float*)LsP4 + c * 1024;
        for (int j16 = 0; j16 < 16; ++j16) {
            int j = half * 16 + j16;
            const floatx4* rJ4 = (const floatx4*)&Ac[c][j][0];
            float s = 0.0f;
#pragma unroll
            for (int q = 0; q < 8; ++q) {
                floatx4 x = rI4[q], y = rJ4[q];
                s = fmaf(x[0], y[0], s); s = fmaf(x[1], y[1], s);
                s = fmaf(x[2], y[2], s); s = fmaf(x[3], y[3], s);
            }
            Pc[i * 32 + j] = s;
        }
    }
    __syncthreads();

    const float* Pw = (const float*)LsP4 + w * 1024;
    float bbv = 0.0f;
    if (lane < ND) {
        for (int j = 0; j < ND; ++j) bbv = fmaf(Pw[lane * 32 + j], mu_s[w][j], bbv);
        bb_s[w][lane] = bbv;
    }
    float ccv = (lane < ND) ? mu_s[w][lane] * bbv : 0.0f;
#pragma unroll
    for (int off = 1; off < 64; off <<= 1) ccv += __shfl_xor(ccv, off);
    int comp = b * NCPB + w;
    if (lane == 0)
        kc[comp] = -0.5f * ccv - 16.0f * LOG2PI - hld;

    if (b == 0 && w == 0) {
        float x = log_weights[lane];
        float mx = x;
#pragma unroll
        for (int off = 1; off < 64; off <<= 1) mx = fmaxf(mx, __shfl_xor(mx, off));
        float e = __expf(x - mx);
#pragma unroll
        for (int off = 1; off < 64; off <<= 1) e += __shfl_xor(e, off);
        lw[lane] = x - mx - logf(e);
    }

    {
        int mt = comp >> 4, colk = comp & 15;
        const float* bbc = &bb_s[w][0];
        bf16x8* qdst = (bf16x8*)Qf;
        {
            int t = lane >> 2, quad = lane & 3;
            bf16x8 v;
            qpack<0>(v, Pw, bbc, t, quad);
            qdst[(size_t)(mt * 18 + t) * 64 + quad * 16 + colk] = v;
        }
        if (lane < 8) {
            int cl2 = 64 + lane;
            int t = cl2 >> 2, quad = cl2 & 3;
            bf16x8 v;
            qpack<0>(v, Pw, bbc, t, quad);
            qdst[(size_t)(mt * 18 + t) * 64 + quad * 16 + colk] = v;
        }
    }
}

// ---------------- main ----------------

template<int G>
__device__ __forceinline__ void fill_x(const float4* p, float (&xr)[ND], int quad) {
    if constexpr (G < 8) {
        float4 v = p[(G + 2 * quad) & 7];
        xr[4 * G + 0] = v.x; xr[4 * G + 1] = v.y;
        xr[4 * G + 2] = v.z; xr[4 * G + 3] = v.w;
        fill_x<G + 1>(p, xr, quad);
    }
}

template<int T, int JJ>
__device__ __forceinline__ void feat(const float (&xr0)[ND], const float (&xr1)[ND],
                                     int quad, floatx8& f0, floatx8& f1) {
    if constexpr (JJ < 8) {
        float a0, a1, b0, b1;
        if constexpr (T < 16) {
            a0 = xr0[JJ]; b0 = xr0[(JJ + T) & 31];
            a1 = xr1[JJ]; b1 = xr1[(JJ + T) & 31];
        } else if constexpr (T == 16) {
            a0 = (quad < 2) ? xr0[JJ] : 1.0f;  b0 = xr0[(JJ + 16) & 31];
            a1 = (quad < 2) ? xr1[JJ] : 1.0f;  b1 = xr1[(JJ + 16) & 31];
        } else {
            a0 = (quad < 2) ? xr0[(JJ + 16) & 31] : 0.0f; b0 = 1.0f;
            a1 = (quad < 2) ? xr1[(JJ + 16) & 31] : 0.0f; b1 = 1.0f;
        }
        f0[JJ] = a0 * b0;
        f1[JJ] = a1 * b1;
        feat<T, JJ + 1>(xr0, xr1, quad, f0, f1);
    }
}

template<int T, int MT>
__device__ __forceinline__ void mfma_step(const unsigned char* qlane, bf16x8 b0, bf16x8 b1,
                                          floatx4 (&A0)[4], floatx4 (&A1)[4]) {
    if constexpr (MT < 4) {
        bf16x8 af = *(const bf16x8*)(qlane + (MT * 18 + T) * 1024);  // ds_read_b128
        A0[MT] = __builtin_amdgcn_mfma_f32_16x16x32_bf16(af, b0, A0[MT], 0, 0, 0);
        A1[MT] = __builtin_amdgcn_mfma_f32_16x16x32_bf16(af, b1, A1[MT], 0, 0, 0);
        mfma_step<T, MT + 1>(qlane, b0, b1, A0, A1);
    }
}

template<int T>
__device__ __forceinline__ void kloop(const unsigned char* qlane,
                                      const float (&xr0)[ND], const float (&xr1)[ND],
                                      int quad, floatx4 (&A0)[4], floatx4 (&A1)[4]) {
    if constexpr (T < 18) {
        floatx8 f0, f1;
        feat<T, 0>(xr0, xr1, quad, f0, f1);
        bf16x8 b0 = __builtin_convertvector(f0, bf16x8);
        bf16x8 b1 = __builtin_convertvector(f1, bf16x8);
        mfma_step<T, 0>(qlane, b0, b1, A0, A1);
        kloop<T + 1>(qlane, xr0, xr1, quad, A0, A1);
    }
}

template<int MT, int R>
__device__ __forceinline__ void epi_r(const floatx4 (&A0)[4], const floatx4 (&A1)[4],
                                      floatx4 lwv, floatx4 kcv,
                                      float& s0, float& w0, float& s1, float& w1) {
    if constexpr (R < 4) {
        float lp0 = A0[MT][R] + kcv[R];
        float e0 = __expf(lp0 + lwv[R]);
        s0 += e0; w0 = fmaf(e0, lp0, w0);
        float lp1 = A1[MT][R] + kcv[R];
        float e1 = __expf(lp1 + lwv[R]);
        s1 += e1; w1 = fmaf(e1, lp1, w1);
        epi_r<MT, R + 1>(A0, A1, lwv, kcv, s0, w0, s1, w1);
    }
}

template<int MT>
__device__ __forceinline__ void epi(const float* lw_s, const float* kc_s, int quad,
                                    const floatx4 (&A0)[4], const floatx4 (&A1)[4],
                                    float& s0, float& w0, float& s1, float& w1) {
    if constexpr (MT < 4) {
        floatx4 lwv = *(const floatx4*)&lw_s[MT * 16 + quad * 4];
        floatx4 kcv = *(const floatx4*)&kc_s[MT * 16 + quad * 4];
        epi_r<MT, 0>(A0, A1, lwv, kcv, s0, w0, s1, w1);
        epi<MT + 1>(lw_s, kc_s, quad, A0, A1, s0, w0, s1, w1);
    }
}

// One 32-sample pair-of-n-tiles: full compute + epilogue, self-contained so
// two sequential calls keep disjoint live ranges (R3/R4 no-spill shape).
__device__ __forceinline__ float pair_ll(const float* __restrict__ X,
                                         const unsigned char* qlane,
                                         const float* lw_s, const float* kc_s,
                                         int n0, int lane, int quad) {
    int n1 = n0 + 16;
    int n0c = n0 < NS ? n0 : NS - 1;
    int n1c = n1 < NS ? n1 : NS - 1;

    float xr0[ND], xr1[ND];
    fill_x<0>((const float4*)(X + (size_t)n0c * ND), xr0, quad);
    fill_x<0>((const float4*)(X + (size_t)n1c * ND), xr1, quad);

    floatx4 A0[4], A1[4];
#pragma unroll
    for (int mt = 0; mt < 4; ++mt) {
        A0[mt] = (floatx4){0.f, 0.f, 0.f, 0.f};
        A1[mt] = (floatx4){0.f, 0.f, 0.f, 0.f};
    }

    kloop<0>(qlane, xr0, xr1, quad, A0, A1);

    float s0 = 0.f, w0 = 0.f, s1 = 0.f, w1 = 0.f;
    epi<0>(lw_s, kc_s, quad, A0, A1, s0, w0, s1, w1);

    s0 += __shfl_xor(s0, 16); s0 += __shfl_xor(s0, 32);
    w0 += __shfl_xor(w0, 16); w0 += __shfl_xor(w0, 32);
    s1 += __shfl_xor(s1, 16); s1 += __shfl_xor(s1, 32);
    w1 += __shfl_xor(w1, 16); w1 += __shfl_xor(w1, 32);

    float ll = 0.0f;
    ll += (n0 < NS) ? (w0 / s0) : 0.0f;
    ll += (n1 < NS) ? (w1 / s1) : 0.0f;
    return ll;
}

// 256 samples per block (2 sequential pairs per wave), Q staged in LDS once
// per block, per-block partial to pb[blockIdx.x]. No atomics, no fences.
__launch_bounds__(256, 2)
__global__ void gmm_main(const float* __restrict__ X,
                         const __bf16* __restrict__ Qf,
                         const float* __restrict__ lw,
                         const float* __restrict__ kc,
                         float* __restrict__ pb) {
    __shared__ __align__(16) unsigned char qlds[QBYTES];   // 72 KB
    __shared__ float lw_s[NC];
    __shared__ float kc_s[NC];
    __shared__ float partial[4];
    int tid = threadIdx.x;
    if (tid < NC) { lw_s[tid] = lw[tid]; kc_s[tid] = kc[tid]; }
    {
        const float4* gsrc = (const float4*)Qf;
        float4* ldst = (float4*)qlds;
#pragma unroll
        for (int i = 0; i < QBYTES / 16 / 256; ++i)
            ldst[i * 256 + tid] = gsrc[i * 256 + tid];
    }
    __syncthreads();

    const int lane = tid & 63;
    const int wave = tid >> 6;
    const int quad = lane >> 4;
    const unsigned char* qlane = qlds + lane * 16;

    int base = blockIdx.x * 256 + wave * 32 + (lane & 15);

    float ll = pair_ll(X, qlane, lw_s, kc_s, base, lane, quad);
    ll      += pair_ll(X, qlane, lw_s, kc_s, base + 128, lane, quad);

    // replicated across 4 quads -> butterfly gives 4x the per-wave sum
#pragma unroll
    for (int off = 1; off < 64; off <<= 1) ll += __shfl_xor(ll, off);
    if (lane == 0) partial[wave] = ll * 0.25f;
    __syncthreads();

    if (tid == 0)
        pb[blockIdx.x] = partial[0] + partial[1] + partial[2] + partial[3];
}

__global__ void gmm_reduce(const float* __restrict__ pb, float* __restrict__ out) {
    int tid = threadIdx.x;   // 256 threads
    float s = 0.0f;
    for (int i = tid; i < NBLK; i += 256) s += pb[i];
#pragma unroll
    for (int off = 32; off > 0; off >>= 1) s += __shfl_down(s, off);
    __shared__ float wsum[4];
    if ((tid & 63) == 0) wsum[tid >> 6] = s;
    __syncthreads();
    if (tid == 0)
        out[0] = -(wsum[0] + wsum[1] + wsum[2] + wsum[3]) / (float)NS;
}

extern "C" void kernel_launch(void* const* d_in, const int* in_sizes, int n_in,
                              void* d_out, int out_size, void* d_ws, size_t ws_size,
                              hipStream_t stream) {
    const float* X           = (const float*)d_in[0];
    const float* means       = (const float*)d_in[1];
    const float* scale_tril  = (const float*)d_in[2];
    const float* log_weights = (const float*)d_in[3];

    char* ws = (char*)d_ws;
    __bf16* Qf = (__bf16*)ws;                  // 73728 B
    float*  lw = (float*)(ws + 73728);
    float*  kc = (float*)(ws + 73984);
    float*  pb = (float*)(ws + 74240);         // NBLK floats

    gmm_setup<<<NC / NCPB, 512, 0, stream>>>(means, scale_tril, log_weights, Qf, lw, kc);
    gmm_main<<<NBLK, 256, 0, stream>>>(X, Qf, lw, kc, pb);
    gmm_reduce<<<1, 256, 0, stream>>>(pb, (float*)d_out);
}

// Round 14
// 93.446 us; speedup vs baseline: 1.4242x; 1.4242x over previous
//
#include <hip/hip_runtime.h>
#include <math.h>

#define NS 100000
#define NC 64
#define ND 32
#define NK 576            // 18 k-tiles of 32 features
#define NBLK ((NS + 255) / 256)     // 391 main blocks, 256 samples each
#define QBYTES (NC * NK * 2)        // 73728 B
#define NCPB 8                      // components per setup block
#define LOG2PI 1.8378770664093453f

typedef __attribute__((ext_vector_type(8))) __bf16 bf16x8;
typedef __attribute__((ext_vector_type(8))) float  floatx8;
typedef __attribute__((ext_vector_type(4))) float  floatx4;

// ws layout (bytes):
//   Qf  [73728 B] : Q in MFMA a-fragment order: chunk (mt*18+t)*64 + quad*16
//         + colk holds 8 bf16 (16 B) for comp mt*16+colk, feats t*32+quad*8+jj.
//   lw  [NC floats] @ 73728 : log_softmax(log_weights)
//   kc  [NC floats] @ 73984 : kconst_k - 0.5*mu^T P mu (fp32)
//   pb  [NBLK floats] @ 74240 : per-block partials (no atomics anywhere)
//
// MEASURED LESSONS:
//  - R13: TWO pairs per wave with LDS-resident Q spilled (WRITE 98.5MB,
//    main 60us): compiler CSE'd the 72 loop-invariant ds_read_b128 frags
//    across both pairs (~288 VGPRs). Fix here: asm memory clobber between
//    pairs forces re-load, keeps VGPR at single-pair level.
//  - R9: runtime-trip-count loops also interleave -> spill. Keep pairs as
//    straight-line calls.
//  - R5/R10: device fences + ticket atomics cost 8-11us. Separate reduce.
//  - R8: LDS-staged Q beats per-wave L2 re-read.
//  - R12 totals: fill 41 (fixed) + gaps ~20 + setup ~4 + reduce ~2.5 +
//    main ~23 (inferred via R13's spilled-main subtraction).

// ---------------- setup (R12, measured ~4us steady-state) -------------------

template<int I, int Q>
__device__ __forceinline__ void load_row(const floatx4* ls4, floatx4 (&rb)[8]) {
    if constexpr (Q <= I / 4) {
        rb[Q] = ls4[I * 8 + Q];
        load_row<I, Q + 1>(ls4, rb);
    }
}

template<int I, int L>
__device__ __forceinline__ void fchain(const floatx4 (&rb)[8], const float (&a)[ND], float& s) {
    if constexpr (L < I) {
        s = fmaf(-rb[L / 4][L % 4], a[L], s);
        fchain<I, L + 1>(rb, a, s);
    }
}

template<int I>
__device__ __forceinline__ void fsub2(const floatx4* ls4, float (&a)[ND], int j) {
    if constexpr (I < ND) {
        floatx4 rb[8];
        load_row<I, 0>(ls4, rb);
        float s = (I == j) ? 1.0f : 0.0f;
        fchain<I, 0>(rb, a, s);
        float v = s / rb[I / 4][I % 4];
        a[I] = (I < j) ? 0.0f : v;
        fsub2<I + 1>(ls4, a, j);
    }
}

template<int Q>
__device__ __forceinline__ void store_ac(float* acrow, const float (&a)[ND]) {
    if constexpr (Q < 8) {
        floatx4 t;
        t[0] = a[4 * Q + 0]; t[1] = a[4 * Q + 1];
        t[2] = a[4 * Q + 2]; t[3] = a[4 * Q + 3];
        *(floatx4*)(acrow + 4 * Q) = t;
        store_ac<Q + 1>(acrow, a);
    }
}

template<int JJ>
__device__ __forceinline__ void qpack(bf16x8& v, const float* Pc, const float* bbc,
                                      int t, int quad) {
    if constexpr (JJ < 8) {
        int u = quad * 8 + JJ;
        float val;
        if (t == 0)       val = -0.5f * Pc[u * 32 + u];
        else if (t < 16)  val = -Pc[u * 32 + ((u + t) & 31)];
        else if (t == 16) val = (u < 16) ? -Pc[u * 32 + u + 16] : bbc[u - 16];
        else              val = (u < 16) ? bbc[16 + u] : 0.0f;
        v[JJ] = (__bf16)val;
        qpack<JJ + 1>(v, Pc, bbc, t, quad);
    }
}

__launch_bounds__(512)
__global__ void gmm_setup(const float* __restrict__ means,
                          const float* __restrict__ scale_tril,
                          const float* __restrict__ log_weights,
                          __bf16* __restrict__ Qf,
                          float* __restrict__ lw,
                          float* __restrict__ kc) {
    __shared__ __align__(16) floatx4 LsP4[NCPB * 256];   // 32 KB: L, later P
    __shared__ __align__(16) float Ac[NCPB][32][36];
    __shared__ float mu_s[NCPB][32];
    __shared__ float bb_s[NCPB][32];

    const int tid  = threadIdx.x;
    const int b    = blockIdx.x;
    const int w    = tid >> 6;
    const int lane = tid & 63;

    {
        const floatx4* g4 = (const floatx4*)scale_tril + (size_t)b * 2048;
#pragma unroll
        for (int q = 0; q < 4; ++q)
            LsP4[q * 512 + tid] = g4[q * 512 + tid];
        if (tid < NCPB * 32)
            mu_s[tid >> 5][tid & 31] = means[(size_t)(b * NCPB + (tid >> 5)) * ND + (tid & 31)];
    }
    __syncthreads();

    const floatx4* ls4 = LsP4 + w * 256;
    if (lane < ND) {
        float a[ND];
        fsub2<0>(ls4, a, lane);
        store_ac<0>(&Ac[w][lane][0], a);
    }
    float hv = (lane < ND) ? logf(((const float*)LsP4)[w * 1024 + lane * 33]) : 0.0f;
#pragma unroll
    for (int off = 1; off < 64; off <<= 1) hv += __shfl_xor(hv, off);
    float hld = hv;
    __syncthreads();

    {
        int c = tid >> 6, half = (tid >> 5) & 1, i = tid & 31;
        const floatx4* rI4 = (const floatx4*)&Ac[c][i][0];
        float* Pc = (float*)LsP4 + c * 1024;
        for (int j16 = 0; j16 < 16; ++j16) {
            int j = half * 16 + j16;
            const floatx4* rJ4 = (const floatx4*)&Ac[c][j][0];
            float s = 0.0f;
#pragma unroll
            for (int q = 0; q < 8; ++q) {
                floatx4 x = rI4[q], y = rJ4[q];
                s = fmaf(x[0], y[0], s); s = fmaf(x[1], y[1], s);
                s = fmaf(x[2], y[2], s); s = fmaf(x[3], y[3], s);
            }
            Pc[i * 32 + j] = s;
        }
    }
    __syncthreads();

    const float* Pw = (const float*)LsP4 + w * 1024;
    float bbv = 0.0f;
    if (lane < ND) {
        for (int j = 0; j < ND; ++j) bbv = fmaf(Pw[lane * 32 + j], mu_s[w][j], bbv);
        bb_s[w][lane] = bbv;
    }
    float ccv = (lane < ND) ? mu_s[w][lane] * bbv : 0.0f;
#pragma unroll
    for (int off = 1; off < 64; off <<= 1) ccv += __shfl_xor(ccv, off);
    int comp = b * NCPB + w;
    if (lane == 0)
        kc[comp] = -0.5f * ccv - 16.0f * LOG2PI - hld;

    if (b == 0 && w == 0) {
        float x = log_weights[lane];
        float mx = x;
#pragma unroll
        for (int off = 1; off < 64; off <<= 1) mx = fmaxf(mx, __shfl_xor(mx, off));
        float e = __expf(x - mx);
#pragma unroll
        for (int off = 1; off < 64; off <<= 1) e += __shfl_xor(e, off);
        lw[lane] = x - mx - logf(e);
    }

    {
        int mt = comp >> 4, colk = comp & 15;
        const float* bbc = &bb_s[w][0];
        bf16x8* qdst = (bf16x8*)Qf;
        {
            int t = lane >> 2, quad = lane & 3;
            bf16x8 v;
            qpack<0>(v, Pw, bbc, t, quad);
            qdst[(size_t)(mt * 18 + t) * 64 + quad * 16 + colk] = v;
        }
        if (lane < 8) {
            int cl2 = 64 + lane;
            int t = cl2 >> 2, quad = cl2 & 3;
            bf16x8 v;
            qpack<0>(v, Pw, bbc, t, quad);
            qdst[(size_t)(mt * 18 + t) * 64 + quad * 16 + colk] = v;
        }
    }
}

// ---------------- main ----------------

template<int G>
__device__ __forceinline__ void fill_x(const float4* p, float (&xr)[ND], int quad) {
    if constexpr (G < 8) {
        float4 v = p[(G + 2 * quad) & 7];
        xr[4 * G + 0] = v.x; xr[4 * G + 1] = v.y;
        xr[4 * G + 2] = v.z; xr[4 * G + 3] = v.w;
        fill_x<G + 1>(p, xr, quad);
    }
}

template<int T, int JJ>
__device__ __forceinline__ void feat(const float (&xr0)[ND], const float (&xr1)[ND],
                                     int quad, floatx8& f0, floatx8& f1) {
    if constexpr (JJ < 8) {
        float a0, a1, b0, b1;
        if constexpr (T < 16) {
            a0 = xr0[JJ]; b0 = xr0[(JJ + T) & 31];
            a1 = xr1[JJ]; b1 = xr1[(JJ + T) & 31];
        } else if constexpr (T == 16) {
            a0 = (quad < 2) ? xr0[JJ] : 1.0f;  b0 = xr0[(JJ + 16) & 31];
            a1 = (quad < 2) ? xr1[JJ] : 1.0f;  b1 = xr1[(JJ + 16) & 31];
        } else {
            a0 = (quad < 2) ? xr0[(JJ + 16) & 31] : 0.0f; b0 = 1.0f;
            a1 = (quad < 2) ? xr1[(JJ + 16) & 31] : 0.0f; b1 = 1.0f;
        }
        f0[JJ] = a0 * b0;
        f1[JJ] = a1 * b1;
        feat<T, JJ + 1>(xr0, xr1, quad, f0, f1);
    }
}

template<int T, int MT>
__device__ __forceinline__ void mfma_step(const unsigned char* qlane, bf16x8 b0, bf16x8 b1,
                                          floatx4 (&A0)[4], floatx4 (&A1)[4]) {
    if constexpr (MT < 4) {
        bf16x8 af = *(const bf16x8*)(qlane + (MT * 18 + T) * 1024);  // ds_read_b128
        A0[MT] = __builtin_amdgcn_mfma_f32_16x16x32_bf16(af, b0, A0[MT], 0, 0, 0);
        A1[MT] = __builtin_amdgcn_mfma_f32_16x16x32_bf16(af, b1, A1[MT], 0, 0, 0);
        mfma_step<T, MT + 1>(qlane, b0, b1, A0, A1);
    }
}

template<int T>
__device__ __forceinline__ void kloop(const unsigned char* qlane,
                                      const float (&xr0)[ND], const float (&xr1)[ND],
                                      int quad, floatx4 (&A0)[4], floatx4 (&A1)[4]) {
    if constexpr (T < 18) {
        floatx8 f0, f1;
        feat<T, 0>(xr0, xr1, quad, f0, f1);
        bf16x8 b0 = __builtin_convertvector(f0, bf16x8);
        bf16x8 b1 = __builtin_convertvector(f1, bf16x8);
        mfma_step<T, 0>(qlane, b0, b1, A0, A1);
        kloop<T + 1>(qlane, xr0, xr1, quad, A0, A1);
    }
}

template<int MT, int R>
__device__ __forceinline__ void epi_r(const floatx4 (&A0)[4], const floatx4 (&A1)[4],
                                      floatx4 lwv, floatx4 kcv,
                                      float& s0, float& w0, float& s1, float& w1) {
    if constexpr (R < 4) {
        float lp0 = A0[MT][R] + kcv[R];
        float e0 = __expf(lp0 + lwv[R]);
        s0 += e0; w0 = fmaf(e0, lp0, w0);
        float lp1 = A1[MT][R] + kcv[R];
        float e1 = __expf(lp1 + lwv[R]);
        s1 += e1; w1 = fmaf(e1, lp1, w1);
        epi_r<MT, R + 1>(A0, A1, lwv, kcv, s0, w0, s1, w1);
    }
}

template<int MT>
__device__ __forceinline__ void epi(const float* lw_s, const float* kc_s, int quad,
                                    const floatx4 (&A0)[4], const floatx4 (&A1)[4],
                                    float& s0, float& w0, float& s1, float& w1) {
    if constexpr (MT < 4) {
        floatx4 lwv = *(const floatx4*)&lw_s[MT * 16 + quad * 4];
        floatx4 kcv = *(const floatx4*)&kc_s[MT * 16 + quad * 4];
        epi_r<MT, 0>(A0, A1, lwv, kcv, s0, w0, s1, w1);
        epi<MT + 1>(lw_s, kc_s, quad, A0, A1, s0, w0, s1, w1);
    }
}

__device__ __forceinline__ float pair_ll(const float* __restrict__ X,
                                         const unsigned char* qlane,
                                         const float* lw_s, const float* kc_s,
                                         int n0, int quad) {
    int n1 = n0 + 16;
    int n0c = n0 < NS ? n0 : NS - 1;
    int n1c = n1 < NS ? n1 : NS - 1;

    float xr0[ND], xr1[ND];
    fill_x<0>((const float4*)(X + (size_t)n0c * ND), xr0, quad);
    fill_x<0>((const float4*)(X + (size_t)n1c * ND), xr1, quad);

    floatx4 A0[4], A1[4];
#pragma unroll
    for (int mt = 0; mt < 4; ++mt) {
        A0[mt] = (floatx4){0.f, 0.f, 0.f, 0.f};
        A1[mt] = (floatx4){0.f, 0.f, 0.f, 0.f};
    }

    kloop<0>(qlane, xr0, xr1, quad, A0, A1);

    float s0 = 0.f, w0 = 0.f, s1 = 0.f, w1 = 0.f;
    epi<0>(lw_s, kc_s, quad, A0, A1, s0, w0, s1, w1);

    s0 += __shfl_xor(s0, 16); s0 += __shfl_xor(s0, 32);
    w0 += __shfl_xor(w0, 16); w0 += __shfl_xor(w0, 32);
    s1 += __shfl_xor(s1, 16); s1 += __shfl_xor(s1, 32);
    w1 += __shfl_xor(w1, 16); w1 += __shfl_xor(w1, 32);

    float ll = 0.0f;
    ll += (n0 < NS) ? (w0 / s0) : 0.0f;
    ll += (n1 < NS) ? (w1 / s1) : 0.0f;
    return ll;
}

// 256 samples per block (2 pairs per wave separated by a compiler memory
// barrier to defeat cross-pair CSE of LDS frag loads -> no spill), Q staged
// in LDS once per block. No atomics, no fences.
__launch_bounds__(256, 2)
__global__ void gmm_main(const float* __restrict__ X,
                         const __bf16* __restrict__ Qf,
                         const float* __restrict__ lw,
                         const float* __restrict__ kc,
                         float* __restrict__ pb) {
    __shared__ __align__(16) unsigned char qlds[QBYTES];   // 72 KB
    __shared__ float lw_s[NC];
    __shared__ float kc_s[NC];
    __shared__ float partial[4];
    int tid = threadIdx.x;
    if (tid < NC) { lw_s[tid] = lw[tid]; kc_s[tid] = kc[tid]; }
    {
        const float4* gsrc = (const float4*)Qf;
        float4* ldst = (float4*)qlds;
#pragma unroll
        for (int i = 0; i < QBYTES / 16 / 256; ++i)
            ldst[i * 256 + tid] = gsrc[i * 256 + tid];
    }
    __syncthreads();

    const int lane = tid & 63;
    const int wave = tid >> 6;
    const int quad = lane >> 4;
    const unsigned char* qlane = qlds + lane * 16;

    int base = blockIdx.x * 256 + wave * 32 + (lane & 15);

    float ll = pair_ll(X, qlane, lw_s, kc_s, base, quad);
    asm volatile("" ::: "memory");   // kill cross-pair CSE/interleave (R13 spill)
    ll      += pair_ll(X, qlane, lw_s, kc_s, base + 128, quad);

    // replicated across 4 quads -> butterfly gives 4x the per-wave sum
#pragma unroll
    for (int off = 1; off < 64; off <<= 1) ll += __shfl_xor(ll, off);
    if (lane == 0) partial[wave] = ll * 0.25f;
    __syncthreads();

    if (tid == 0)
        pb[blockIdx.x] = partial[0] + partial[1] + partial[2] + partial[3];
}

__global__ void gmm_reduce(const float* __restrict__ pb, float* __restrict__ out) {
    int tid = threadIdx.x;   // 256 threads
    float s = 0.0f;
    for (int i = tid; i < NBLK; i += 256) s += pb[i];
#pragma unroll
    for (int off = 32; off > 0; off >>= 1) s += __shfl_down(s, off);
    __shared__ float wsum[4];
    if ((tid & 63) == 0) wsum[tid >> 6] = s;
    __syncthreads();
    if (tid == 0)
        out[0] = -(wsum[0] + wsum[1] + wsum[2] + wsum[3]) / (float)NS;
}

extern "C" void kernel_launch(void* const* d_in, const int* in_sizes, int n_in,
                              void* d_out, int out_size, void* d_ws, size_t ws_size,
                              hipStream_t stream) {
    const float* X           = (const float*)d_in[0];
    const float* means       = (const float*)d_in[1];
    const float* scale_tril  = (const float*)d_in[2];
    const float* log_weights = (const float*)d_in[3];

    char* ws = (char*)d_ws;
    __bf16* Qf = (__bf16*)ws;                  // 73728 B
    float*  lw = (float*)(ws + 73728);
    float*  kc = (float*)(ws + 73984);
    float*  pb = (float*)(ws + 74240);         // NBLK floats

    gmm_setup<<<NC / NCPB, 512, 0, stream>>>(means, scale_tril, log_weights, Qf, lw, kc);
    gmm_main<<<NBLK, 256, 0, stream>>>(X, Qf, lw, kc, pb);
    gmm_reduce<<<1, 256, 0, stream>>>(pb, (float*)d_out);
}